// Round 3
// baseline (88.537 us; speedup 1.0000x reference)
//
#include <hip/hip_runtime.h>

// Table-batched embedding-bag, SUM pooling.
// weights: [T=8, E=250000, D=128] fp32
// indices: [T, B=4096, L=32] int32 (harness delivers integer inputs as int32)
// out:     [B, T*D] fp32, out[b, t*D + d] = sum_l weights[t, idx[t,b,l], d]

#define T_TABLES 8
#define E_ROWS   250000
#define D_DIM    128
#define B_BAGS   4096
#define L_POOL   32

// One half-wave (32 lanes) per bag; each lane owns a float4 (4 floats of D).
// 32 lanes x 16 B = 512 B = one full embedding row per vector load -> fully
// coalesced. Block = 256 threads = 8 bags.
__global__ __launch_bounds__(256) void embed_bag_pool_kernel(
    const float* __restrict__ weights,
    const int*   __restrict__ indices,
    float*       __restrict__ out)
{
    const int tid    = threadIdx.x;
    const int group  = tid >> 5;      // half-wave id within block: 0..7
    const int lane32 = tid & 31;      // lane within half-wave

    // bag id = t*B + b ; 8 bags per block
    const unsigned bag = blockIdx.x * 8u + (unsigned)group;
    const int t = (int)(bag / B_BAGS);
    const int b = (int)(bag % B_BAGS);

    const int* bag_idx = indices + ((size_t)t * B_BAGS + (size_t)b) * L_POOL;
    const float4* w_t  = (const float4*)(weights + (size_t)t * E_ROWS * D_DIM);
    // row stride in float4 units: D/4 = 32

    // Each lane loads one of the 32 indices; broadcast within the half-wave
    // via shuffle (no LDS, no redundant global reads).
    int my_idx = bag_idx[lane32];

    float4 acc = make_float4(0.f, 0.f, 0.f, 0.f);

#pragma unroll
    for (int l = 0; l < L_POOL; ++l) {
        int row = __shfl(my_idx, l, 32);
        float4 v = w_t[(size_t)row * (D_DIM / 4) + lane32];
        acc.x += v.x;
        acc.y += v.y;
        acc.z += v.z;
        acc.w += v.w;
    }

    // out[b, t*D + 4*lane32 .. +3] -- 512 B coalesced store per half-wave.
    float4* outp = (float4*)(out + (size_t)b * (T_TABLES * D_DIM)
                                 + (size_t)t * D_DIM);
    outp[lane32] = acc;
}

extern "C" void kernel_launch(void* const* d_in, const int* in_sizes, int n_in,
                              void* d_out, int out_size, void* d_ws, size_t ws_size,
                              hipStream_t stream) {
    const float* weights = (const float*)d_in[0];
    const int*   indices = (const int*)d_in[1];
    float*       out     = (float*)d_out;

    const int total_bags = T_TABLES * B_BAGS;          // 32768
    const int blocks     = total_bags / 8;             // 4096 blocks of 256 thr

    embed_bag_pool_kernel<<<blocks, 256, 0, stream>>>(weights, indices, out);
}